// Round 2
// baseline (489.906 us; speedup 1.0000x reference)
//
#include <hip/hip_runtime.h>
#include <hip/hip_bf16.h>

#define BATCH 256
#define NDIM  4096
#define STEPS 16
#define EPS_RMS 1.1920929e-07f

typedef _Float16 f16x8 __attribute__((ext_vector_type(8)));
typedef float  f32x4  __attribute__((ext_vector_type(4)));
typedef unsigned short u16x4 __attribute__((ext_vector_type(4)));
typedef unsigned int   u32x4 __attribute__((ext_vector_type(4)));

__device__ __forceinline__ unsigned short f2h(float f) {
  _Float16 h = (_Float16)f;
  union { _Float16 h; unsigned short u; } v; v.h = h; return v.u;
}

__device__ __forceinline__ float block_reduce_sum(float v) {
  __shared__ float ws[4];
  __shared__ float tot;
  #pragma unroll
  for (int off = 32; off > 0; off >>= 1) v += __shfl_down(v, off, 64);
  int lane = threadIdx.x & 63, w = threadIdx.x >> 6;
  if (lane == 0) ws[w] = v;
  __syncthreads();
  if (threadIdx.x == 0) tot = ws[0] + ws[1] + ws[2] + ws[3];
  __syncthreads();
  return tot;
}

// ---------------- W (f32, [k][n]) -> Wt (fp16, [n][k]) ----------------
__global__ __launch_bounds__(256) void transpose_w(
    const float* __restrict__ W, unsigned short* __restrict__ Wt) {
  __shared__ float tile[64][65];
  int n0 = blockIdx.x * 64;  // W col block
  int k0 = blockIdx.y * 64;  // W row block
  int t = threadIdx.x;
  int r = t >> 4, c4 = (t & 15) * 4;
  #pragma unroll
  for (int p = 0; p < 4; ++p) {
    f32x4 v = *(const f32x4*)(W + (size_t)(k0 + r + 16 * p) * NDIM + n0 + c4);
    tile[r + 16 * p][c4 + 0] = v[0];
    tile[r + 16 * p][c4 + 1] = v[1];
    tile[r + 16 * p][c4 + 2] = v[2];
    tile[r + 16 * p][c4 + 3] = v[3];
  }
  __syncthreads();
  #pragma unroll
  for (int p = 0; p < 4; ++p) {
    int nr = r + 16 * p;
    u16x4 o;
    #pragma unroll
    for (int j = 0; j < 4; ++j) o[j] = f2h(tile[c4 + j][nr]);
    *(u16x4*)(Wt + (size_t)(n0 + nr) * NDIM + k0 + c4) = o;
  }
}

// ---------------- column multipliers from scatter positions ----------------
__global__ void init_colmul(const float* __restrict__ iscale,
                            const float* __restrict__ oscale,
                            const int* __restrict__ ipos, const int* __restrict__ opos,
                            float* __restrict__ icm, float* __restrict__ ocm) {
  int c = blockIdx.x * 256 + threadIdx.x;
  if (c >= NDIM) return;
  float iv = 1.f, ov = 1.f;
  #pragma unroll
  for (int i = 0; i < 16; ++i) {
    if (ipos[i] == c) iv *= iscale[i];
    if (opos[i] == c) ov *= oscale[i];
  }
  icm[c] = iv; ocm[c] = ov;
}

// ---------------- step 0: h1 = norm(tanh(B + x*icm)) ----------------
__global__ __launch_bounds__(256) void step0_kernel(
    const float* __restrict__ x, const float* __restrict__ bias,
    const float* __restrict__ icm, const float* __restrict__ nw,
    const float* __restrict__ ocm,
    unsigned short* __restrict__ hbuf, float* __restrict__ out) {
  int row = blockIdx.x;
  int tid = threadIdx.x;
  const float* xr = x + (size_t)row * NDIM;
  float a[16];
  float sq = 0.f;
  #pragma unroll
  for (int p = 0; p < 4; ++p) {
    int c = p * 1024 + tid * 4;
    f32x4 xv = *(const f32x4*)(xr + c);
    f32x4 bv = *(const f32x4*)(bias + c);
    f32x4 ic = *(const f32x4*)(icm + c);
    #pragma unroll
    for (int j = 0; j < 4; ++j) {
      float av = tanhf(bv[j] + xv[j] * ic[j]);
      a[p * 4 + j] = av;
      sq += av * av;
    }
  }
  float tot = block_reduce_sum(sq);
  float scale = rsqrtf(tot * (1.0f / NDIM) + EPS_RMS);
  unsigned short* hrow = hbuf + (size_t)row * NDIM;
  float* orow = out + (size_t)row * STEPS * NDIM;  // t = 0
  #pragma unroll
  for (int p = 0; p < 4; ++p) {
    int c = p * 1024 + tid * 4;
    f32x4 nv = *(const f32x4*)(nw + c);
    f32x4 oc = *(const f32x4*)(ocm + c);
    u16x4 hs; f32x4 os;
    #pragma unroll
    for (int j = 0; j < 4; ++j) {
      float h = a[p * 4 + j] * scale * nv[j];
      hs[j] = f2h(h);
      os[j] = h * oc[j];
    }
    *(u16x4*)(hrow + c) = hs;
    *(f32x4*)(orow + c) = os;
  }
}

// ---------------- GEMM: pbuf[ks] = (h @ W)[128x128 tile, K-slice], fp16 MFMA ----------------
#define BK 64
#define LSTR 72

__global__ __launch_bounds__(256, 1) void gemm_kernel(
    const unsigned short* __restrict__ A,   // h fp16 [256][4096]
    const unsigned short* __restrict__ Bt,  // Wt fp16 [n][k]
    float* __restrict__ pbuf) {             // [4][256][4096] f32
  __shared__ __align__(16) unsigned short As[128 * LSTR];
  __shared__ __align__(16) unsigned short Bs[128 * LSTR];
  int tid = threadIdx.x;
  int n0 = blockIdx.x * 128;   // 0..31
  int m0 = blockIdx.y * 128;   // 0..1
  int ks = blockIdx.z;         // 0..3
  int kbase = ks * 1024;
  int wave = tid >> 6, lane = tid & 63;
  int wm = (wave >> 1) * 64, wn = (wave & 1) * 64;
  int l15 = lane & 15, lk = (lane >> 4) * 8;
  int rb = tid >> 3, c8 = (tid & 7) * 8;

  f32x4 acc[4][4];
  f32x4 zero = {0.f, 0.f, 0.f, 0.f};
  #pragma unroll
  for (int i = 0; i < 4; ++i)
    #pragma unroll
    for (int j = 0; j < 4; ++j) acc[i][j] = zero;

  u32x4 aR[4], bR[4];
  {
    int kb = kbase;
    #pragma unroll
    for (int p = 0; p < 4; ++p) {
      aR[p] = *(const u32x4*)(A  + (size_t)(m0 + rb + 32 * p) * NDIM + kb + c8);
      bR[p] = *(const u32x4*)(Bt + (size_t)(n0 + rb + 32 * p) * NDIM + kb + c8);
    }
  }

  for (int it = 0; it < 16; ++it) {
    __syncthreads();
    #pragma unroll
    for (int p = 0; p < 4; ++p) {
      *(u32x4*)&As[(rb + 32 * p) * LSTR + c8] = aR[p];
      *(u32x4*)&Bs[(rb + 32 * p) * LSTR + c8] = bR[p];
    }
    __syncthreads();
    if (it < 15) {
      int kb = kbase + (it + 1) * BK;
      #pragma unroll
      for (int p = 0; p < 4; ++p) {
        aR[p] = *(const u32x4*)(A  + (size_t)(m0 + rb + 32 * p) * NDIM + kb + c8);
        bR[p] = *(const u32x4*)(Bt + (size_t)(n0 + rb + 32 * p) * NDIM + kb + c8);
      }
    }
    #pragma unroll
    for (int kk = 0; kk < 2; ++kk) {
      f16x8 af[4], bfr[4];
      #pragma unroll
      for (int mf = 0; mf < 4; ++mf)
        af[mf] = *(const f16x8*)&As[(wm + mf * 16 + l15) * LSTR + kk * 32 + lk];
      #pragma unroll
      for (int nf = 0; nf < 4; ++nf)
        bfr[nf] = *(const f16x8*)&Bs[(wn + nf * 16 + l15) * LSTR + kk * 32 + lk];
      #pragma unroll
      for (int mf = 0; mf < 4; ++mf)
        #pragma unroll
        for (int nf = 0; nf < 4; ++nf)
          acc[mf][nf] = __builtin_amdgcn_mfma_f32_16x16x32_f16(af[mf], bfr[nf], acc[mf][nf], 0, 0, 0);
    }
  }

  float* pout = pbuf + (size_t)ks * BATCH * NDIM;
  int crow = (lane >> 4) * 4;
  #pragma unroll
  for (int mf = 0; mf < 4; ++mf) {
    #pragma unroll
    for (int nf = 0; nf < 4; ++nf) {
      int col = n0 + wn + nf * 16 + l15;
      #pragma unroll
      for (int r = 0; r < 4; ++r) {
        int row = m0 + wm + mf * 16 + crow + r;
        pout[(size_t)row * NDIM + col] = acc[mf][nf][r];
      }
    }
  }
}

// ---------------- combine splits + bias + tanh + RMSNorm + outputs ----------------
__global__ __launch_bounds__(256) void normalize_kernel(
    const float* __restrict__ pbuf, const float* __restrict__ bias,
    const float* __restrict__ nw, const float* __restrict__ ocm,
    unsigned short* __restrict__ hbuf, float* __restrict__ out,
    float* __restrict__ hfin, int t, int is_last) {
  const size_t SL = (size_t)BATCH * NDIM;
  int row = blockIdx.x;
  int tid = threadIdx.x;
  const float* p0 = pbuf + (size_t)row * NDIM;
  float a[16];
  float sq = 0.f;
  #pragma unroll
  for (int p = 0; p < 4; ++p) {
    int c = p * 1024 + tid * 4;
    f32x4 s = *(const f32x4*)(p0 + c);
    s += *(const f32x4*)(p0 + SL + c);
    s += *(const f32x4*)(p0 + 2 * SL + c);
    s += *(const f32x4*)(p0 + 3 * SL + c);
    f32x4 bv = *(const f32x4*)(bias + c);
    #pragma unroll
    for (int j = 0; j < 4; ++j) {
      float av = tanhf(s[j] + bv[j]);
      a[p * 4 + j] = av;
      sq += av * av;
    }
  }
  float tot = block_reduce_sum(sq);
  float scale = rsqrtf(tot * (1.0f / NDIM) + EPS_RMS);
  unsigned short* hrow = hbuf + (size_t)row * NDIM;
  float* orow = out + ((size_t)row * STEPS + t) * NDIM;
  #pragma unroll
  for (int p = 0; p < 4; ++p) {
    int c = p * 1024 + tid * 4;
    f32x4 nv = *(const f32x4*)(nw + c);
    f32x4 oc = *(const f32x4*)(ocm + c);
    u16x4 hs; f32x4 os;
    #pragma unroll
    for (int j = 0; j < 4; ++j) {
      float h = a[p * 4 + j] * scale * nv[j];
      hs[j] = f2h(h);
      os[j] = h * oc[j];
    }
    *(u16x4*)(hrow + c) = hs;
    *(f32x4*)(orow + c) = os;
    if (is_last) *(f32x4*)(hfin + (size_t)row * NDIM + c) = *(f32x4*)&a[p*4] * scale * nv;
  }
}

extern "C" void kernel_launch(void* const* d_in, const int* in_sizes, int n_in,
                              void* d_out, int out_size, void* d_ws, size_t ws_size,
                              hipStream_t stream) {
  (void)in_sizes; (void)n_in; (void)out_size; (void)ws_size;
  const float* x      = (const float*)d_in[0];
  const float* W      = (const float*)d_in[1];
  const float* Bb     = (const float*)d_in[2];
  const float* iscale = (const float*)d_in[3];
  const float* oscale = (const float*)d_in[4];
  const float* nw     = (const float*)d_in[5];
  const int* ipos = (const int*)d_in[6];
  const int* opos = (const int*)d_in[7];
  // d_in[8] = steps (fixed at 16 by the problem spec).

  char* ws = (char*)d_ws;
  unsigned short* Wt   = (unsigned short*)(ws);                    // 32 MiB fp16
  unsigned short* hbuf = (unsigned short*)(ws + 33554432);         // 2 MiB fp16
  float* icm           = (float*)(ws + 35651584);                  // 16 KiB
  float* ocm           = (float*)(ws + 35667968);                  // 16 KiB
  float* pbuf          = (float*)(ws + 35684352);                  // 16 MiB

  float* out  = (float*)d_out;
  float* hfin = out + (size_t)BATCH * STEPS * NDIM;

  hipLaunchKernelGGL(transpose_w, dim3(64, 64), dim3(256), 0, stream, W, Wt);
  hipLaunchKernelGGL(init_colmul, dim3(16), dim3(256), 0, stream,
                     iscale, oscale, ipos, opos, icm, ocm);
  hipLaunchKernelGGL(step0_kernel, dim3(256), dim3(256), 0, stream,
                     x, Bb, icm, nw, ocm, hbuf, out);
  for (int t = 1; t < STEPS; ++t) {
    hipLaunchKernelGGL(gemm_kernel, dim3(32, 2, 4), dim3(256), 0, stream,
                       hbuf, Wt, pbuf);
    hipLaunchKernelGGL(normalize_kernel, dim3(256), dim3(256), 0, stream,
                       pbuf, Bb, nw, ocm, hbuf, out, hfin, t, (t == STEPS - 1) ? 1 : 0);
  }
}

// Round 3
// 435.063 us; speedup vs baseline: 1.1261x; 1.1261x over previous
//
#include <hip/hip_runtime.h>
#include <hip/hip_bf16.h>

#define BATCH 256
#define NDIM  4096
#define STEPS 16
#define EPS_RMS 1.1920929e-07f

typedef _Float16 f16x8 __attribute__((ext_vector_type(8)));
typedef float  f32x4  __attribute__((ext_vector_type(4)));
typedef unsigned short u16x4 __attribute__((ext_vector_type(4)));
typedef unsigned int   u32x4 __attribute__((ext_vector_type(4)));

__device__ __forceinline__ unsigned short f2h(float f) {
  _Float16 h = (_Float16)f;
  union { _Float16 h; unsigned short u; } v; v.h = h; return v.u;
}

// block-wide sum for 512-thread blocks (8 waves)
__device__ __forceinline__ float block_reduce_sum_512(float v) {
  __shared__ float ws[8];
  __shared__ float tot;
  #pragma unroll
  for (int off = 32; off > 0; off >>= 1) v += __shfl_down(v, off, 64);
  int lane = threadIdx.x & 63, w = threadIdx.x >> 6;
  if (lane == 0) ws[w] = v;
  __syncthreads();
  if (threadIdx.x == 0) {
    float t = 0.f;
    #pragma unroll
    for (int i = 0; i < 8; ++i) t += ws[i];
    tot = t;
  }
  __syncthreads();
  return tot;
}

// ---------------- W (f32, [k][n]) -> Wt (fp16, [n][k]) ----------------
__global__ __launch_bounds__(256) void transpose_w(
    const float* __restrict__ W, unsigned short* __restrict__ Wt) {
  __shared__ float tile[64][65];
  int n0 = blockIdx.x * 64;
  int k0 = blockIdx.y * 64;
  int t = threadIdx.x;
  int r = t >> 4, c4 = (t & 15) * 4;
  #pragma unroll
  for (int p = 0; p < 4; ++p) {
    f32x4 v = *(const f32x4*)(W + (size_t)(k0 + r + 16 * p) * NDIM + n0 + c4);
    tile[r + 16 * p][c4 + 0] = v[0];
    tile[r + 16 * p][c4 + 1] = v[1];
    tile[r + 16 * p][c4 + 2] = v[2];
    tile[r + 16 * p][c4 + 3] = v[3];
  }
  __syncthreads();
  #pragma unroll
  for (int p = 0; p < 4; ++p) {
    int nr = r + 16 * p;
    u16x4 o;
    #pragma unroll
    for (int j = 0; j < 4; ++j) o[j] = f2h(tile[c4 + j][nr]);
    *(u16x4*)(Wt + (size_t)(n0 + nr) * NDIM + k0 + c4) = o;
  }
}

// ---------------- column multipliers from scatter positions ----------------
__global__ void init_colmul(const float* __restrict__ iscale,
                            const float* __restrict__ oscale,
                            const int* __restrict__ ipos, const int* __restrict__ opos,
                            float* __restrict__ icm, float* __restrict__ ocm) {
  int c = blockIdx.x * 256 + threadIdx.x;
  if (c >= NDIM) return;
  float iv = 1.f, ov = 1.f;
  #pragma unroll
  for (int i = 0; i < 16; ++i) {
    if (ipos[i] == c) iv *= iscale[i];
    if (opos[i] == c) ov *= oscale[i];
  }
  icm[c] = iv; ocm[c] = ov;
}

// ---------------- step 0: h1 = norm(tanh(B + x*icm)) ----------------
__global__ __launch_bounds__(512) void step0_kernel(
    const float* __restrict__ x, const float* __restrict__ bias,
    const float* __restrict__ icm, const float* __restrict__ nw,
    const float* __restrict__ ocm,
    unsigned short* __restrict__ hbuf, float* __restrict__ out) {
  int row = blockIdx.x;
  int tid = threadIdx.x;
  const float* xr = x + (size_t)row * NDIM;
  float a[8];
  float sq = 0.f;
  #pragma unroll
  for (int p = 0; p < 2; ++p) {
    int c = p * 2048 + tid * 4;
    f32x4 xv = *(const f32x4*)(xr + c);
    f32x4 bv = *(const f32x4*)(bias + c);
    f32x4 ic = *(const f32x4*)(icm + c);
    #pragma unroll
    for (int j = 0; j < 4; ++j) {
      float av = tanhf(bv[j] + xv[j] * ic[j]);
      a[p * 4 + j] = av;
      sq += av * av;
    }
  }
  float tot = block_reduce_sum_512(sq);
  float scale = rsqrtf(tot * (1.0f / NDIM) + EPS_RMS);
  unsigned short* hrow = hbuf + (size_t)row * NDIM;
  float* orow = out + (size_t)row * STEPS * NDIM;  // t = 0
  #pragma unroll
  for (int p = 0; p < 2; ++p) {
    int c = p * 2048 + tid * 4;
    f32x4 nv = *(const f32x4*)(nw + c);
    f32x4 oc = *(const f32x4*)(ocm + c);
    u16x4 hs; f32x4 os;
    #pragma unroll
    for (int j = 0; j < 4; ++j) {
      float h = a[p * 4 + j] * scale * nv[j];
      hs[j] = f2h(h);
      os[j] = h * oc[j];
    }
    *(u16x4*)(hrow + c) = hs;
    *(f32x4*)(orow + c) = os;
  }
}

// ---------------- GEMM: pbuf[ks] = (h @ W)[64x128 tile, K-slice], fp16 MFMA ----------------
// grid (32, 4, KSPLIT), block 256 = 4 waves (2x2), 4 blocks/CU at KSPLIT=8.
#define BK 64
#define LSTR 72

__global__ __launch_bounds__(256, 4) void gemm_kernel(
    const unsigned short* __restrict__ A,   // h fp16 [256][4096]
    const unsigned short* __restrict__ Bt,  // Wt fp16 [n][k]
    float* __restrict__ pbuf,               // [KSPLIT][256][4096] f32
    int kslen) {                            // K per slice (512 or 1024)
  __shared__ __align__(16) unsigned short As[64 * LSTR];
  __shared__ __align__(16) unsigned short Bs[128 * LSTR];
  int tid = threadIdx.x;
  int n0 = blockIdx.x * 128;   // 0..31
  int m0 = blockIdx.y * 64;    // 0..3
  int ks = blockIdx.z;
  int kbase = ks * kslen;
  int nit = kslen >> 6;        // K-iterations of BK=64
  int wave = tid >> 6, lane = tid & 63;
  int wm = (wave >> 1) * 32, wn = (wave & 1) * 64;
  int l15 = lane & 15, lk = (lane >> 4) * 8;
  int rb = tid >> 3, c8 = (tid & 7) * 8;   // rb 0..31, c8 0..56

  f32x4 acc[2][4];
  f32x4 zero = {0.f, 0.f, 0.f, 0.f};
  #pragma unroll
  for (int i = 0; i < 2; ++i)
    #pragma unroll
    for (int j = 0; j < 4; ++j) acc[i][j] = zero;

  u32x4 aR[2], bR[4];
  {
    #pragma unroll
    for (int p = 0; p < 2; ++p)
      aR[p] = *(const u32x4*)(A  + (size_t)(m0 + rb + 32 * p) * NDIM + kbase + c8);
    #pragma unroll
    for (int p = 0; p < 4; ++p)
      bR[p] = *(const u32x4*)(Bt + (size_t)(n0 + rb + 32 * p) * NDIM + kbase + c8);
  }

  for (int it = 0; it < nit; ++it) {
    __syncthreads();
    #pragma unroll
    for (int p = 0; p < 2; ++p)
      *(u32x4*)&As[(rb + 32 * p) * LSTR + c8] = aR[p];
    #pragma unroll
    for (int p = 0; p < 4; ++p)
      *(u32x4*)&Bs[(rb + 32 * p) * LSTR + c8] = bR[p];
    __syncthreads();
    if (it < nit - 1) {
      int kb = kbase + (it + 1) * BK;
      #pragma unroll
      for (int p = 0; p < 2; ++p)
        aR[p] = *(const u32x4*)(A  + (size_t)(m0 + rb + 32 * p) * NDIM + kb + c8);
      #pragma unroll
      for (int p = 0; p < 4; ++p)
        bR[p] = *(const u32x4*)(Bt + (size_t)(n0 + rb + 32 * p) * NDIM + kb + c8);
    }
    #pragma unroll
    for (int kk = 0; kk < 2; ++kk) {
      f16x8 af[2], bfr[4];
      #pragma unroll
      for (int mf = 0; mf < 2; ++mf)
        af[mf] = *(const f16x8*)&As[(wm + mf * 16 + l15) * LSTR + kk * 32 + lk];
      #pragma unroll
      for (int nf = 0; nf < 4; ++nf)
        bfr[nf] = *(const f16x8*)&Bs[(wn + nf * 16 + l15) * LSTR + kk * 32 + lk];
      #pragma unroll
      for (int mf = 0; mf < 2; ++mf)
        #pragma unroll
        for (int nf = 0; nf < 4; ++nf)
          acc[mf][nf] = __builtin_amdgcn_mfma_f32_16x16x32_f16(af[mf], bfr[nf], acc[mf][nf], 0, 0, 0);
    }
  }

  float* pout = pbuf + (size_t)ks * BATCH * NDIM;
  int crow = (lane >> 4) * 4;
  #pragma unroll
  for (int mf = 0; mf < 2; ++mf) {
    #pragma unroll
    for (int nf = 0; nf < 4; ++nf) {
      int col = n0 + wn + nf * 16 + l15;
      #pragma unroll
      for (int r = 0; r < 4; ++r) {
        int row = m0 + wm + mf * 16 + crow + r;
        pout[(size_t)row * NDIM + col] = acc[mf][nf][r];
      }
    }
  }
}

// ---------------- combine splits + bias + tanh + RMSNorm + outputs ----------------
__global__ __launch_bounds__(512) void normalize_kernel(
    const float* __restrict__ pbuf, const float* __restrict__ bias,
    const float* __restrict__ nw, const float* __restrict__ ocm,
    unsigned short* __restrict__ hbuf, float* __restrict__ out,
    float* __restrict__ hfin, int t, int is_last, int ksplit) {
  const size_t SL = (size_t)BATCH * NDIM;
  int row = blockIdx.x;
  int tid = threadIdx.x;
  const float* p0 = pbuf + (size_t)row * NDIM;
  float a[8];
  float sq = 0.f;
  #pragma unroll
  for (int p = 0; p < 2; ++p) {
    int c = p * 2048 + tid * 4;
    f32x4 s = *(const f32x4*)(p0 + c);
    for (int k = 1; k < ksplit; ++k)
      s += *(const f32x4*)(p0 + (size_t)k * SL + c);
    f32x4 bv = *(const f32x4*)(bias + c);
    #pragma unroll
    for (int j = 0; j < 4; ++j) {
      float av = tanhf(s[j] + bv[j]);
      a[p * 4 + j] = av;
      sq += av * av;
    }
  }
  float tot = block_reduce_sum_512(sq);
  float scale = rsqrtf(tot * (1.0f / NDIM) + EPS_RMS);
  unsigned short* hrow = hbuf + (size_t)row * NDIM;
  float* orow = out + ((size_t)row * STEPS + t) * NDIM;
  #pragma unroll
  for (int p = 0; p < 2; ++p) {
    int c = p * 2048 + tid * 4;
    f32x4 nv = *(const f32x4*)(nw + c);
    f32x4 oc = *(const f32x4*)(ocm + c);
    u16x4 hs; f32x4 os; f32x4 hv;
    #pragma unroll
    for (int j = 0; j < 4; ++j) {
      float h = a[p * 4 + j] * scale * nv[j];
      hv[j] = h;
      hs[j] = f2h(h);
      os[j] = h * oc[j];
    }
    *(u16x4*)(hrow + c) = hs;
    *(f32x4*)(orow + c) = os;
    if (is_last) *(f32x4*)(hfin + (size_t)row * NDIM + c) = hv;
  }
}

extern "C" void kernel_launch(void* const* d_in, const int* in_sizes, int n_in,
                              void* d_out, int out_size, void* d_ws, size_t ws_size,
                              hipStream_t stream) {
  (void)in_sizes; (void)n_in; (void)out_size;
  const float* x      = (const float*)d_in[0];
  const float* W      = (const float*)d_in[1];
  const float* Bb     = (const float*)d_in[2];
  const float* iscale = (const float*)d_in[3];
  const float* oscale = (const float*)d_in[4];
  const float* nw     = (const float*)d_in[5];
  const int* ipos = (const int*)d_in[6];
  const int* opos = (const int*)d_in[7];
  // d_in[8] = steps (fixed at 16 by the problem spec).

  char* ws = (char*)d_ws;
  unsigned short* Wt   = (unsigned short*)(ws);                    // 32 MiB fp16
  unsigned short* hbuf = (unsigned short*)(ws + 33554432);         // 2 MiB fp16
  float* icm           = (float*)(ws + 35651584);                  // 16 KiB
  float* ocm           = (float*)(ws + 35667968);                  // 16 KiB
  float* pbuf          = (float*)(ws + 35684352);                  // up to 32 MiB

  // splitK=8 needs pbuf of 32 MiB -> ~66 MiB total; fall back to 4 if ws is tight.
  size_t need8 = 35684352 + (size_t)8 * BATCH * NDIM * sizeof(float);
  int ksplit = (ws_size >= need8) ? 8 : 4;
  int kslen = NDIM / ksplit;

  float* out  = (float*)d_out;
  float* hfin = out + (size_t)BATCH * STEPS * NDIM;

  hipLaunchKernelGGL(transpose_w, dim3(64, 64), dim3(256), 0, stream, W, Wt);
  hipLaunchKernelGGL(init_colmul, dim3(16), dim3(256), 0, stream,
                     iscale, oscale, ipos, opos, icm, ocm);
  hipLaunchKernelGGL(step0_kernel, dim3(256), dim3(512), 0, stream,
                     x, Bb, icm, nw, ocm, hbuf, out);
  for (int t = 1; t < STEPS; ++t) {
    hipLaunchKernelGGL(gemm_kernel, dim3(32, 4, ksplit), dim3(256), 0, stream,
                       hbuf, Wt, pbuf, kslen);
    hipLaunchKernelGGL(normalize_kernel, dim3(256), dim3(512), 0, stream,
                       pbuf, Bb, nw, ocm, hbuf, out, hfin, t, (t == STEPS - 1) ? 1 : 0, ksplit);
  }
}